// Round 9
// baseline (504.634 us; speedup 1.0000x reference)
//
#include <hip/hip_runtime.h>
#include <cstdint>
#include <cstddef>

#define DF 128
#define NEG 0.01f
#define PAD 16   // one atomic counter per 64-B cache line
typedef unsigned int u32;

struct f2 { float x, y; };
static __device__ __forceinline__ f2 ld2(const float* p) { return *(const f2*)p; }
static __device__ __forceinline__ void st2(float* p, f2 v) { *(f2*)p = v; }

// packed bf16 pair <-> floats (element 0 in low 16 bits), round-to-nearest-even
static __device__ __forceinline__ void ubf(u32 p, float& a, float& b) {
    a = __uint_as_float(p << 16);
    b = __uint_as_float(p & 0xffff0000u);
}
static __device__ __forceinline__ u32 pbf(float a, float b) {
    u32 ua = __float_as_uint(a), ub = __float_as_uint(b);
    ua += 0x7fffu + ((ua >> 16) & 1u);
    ub += 0x7fffu + ((ub >> 16) & 1u);
    return (ua >> 16) | (ub & 0xffff0000u);
}
static __device__ __forceinline__ unsigned short f2bf(float v) {
    u32 ua = __float_as_uint(v);
    ua += 0x7fffu + ((ua >> 16) & 1u);
    return (unsigned short)(ua >> 16);
}
static __device__ __forceinline__ int decode_m(int raw) {
    return (raw == 1 || raw == 16256 || raw == 1065353216) ? 1
         : (raw > 1 && raw < 16) ? raw : 1;
}

typedef __attribute__((ext_vector_type(8))) short s8v;
typedef __attribute__((ext_vector_type(4))) float f4v;

static __device__ __forceinline__ s8v pack8(const float* p) {
    union { u32 u[4]; s8v v; } r;
    r.u[0] = pbf(p[0], p[1]); r.u[1] = pbf(p[2], p[3]);
    r.u[2] = pbf(p[4], p[5]); r.u[3] = pbf(p[6], p[7]);
    return r.v;
}
static __device__ __forceinline__ s8v load8p(const u32* p) {
    union { uint4 u; s8v v; } r;
    r.u = *(const uint4*)p;
    return r.v;
}

__global__ void k_sentinel(float* out, int n) {
    int i = blockIdx.x * blockDim.x + threadIdx.x;
    if (i < n) out[i] = 12345.0f;
}

// Degree counting onto line-padded counters (chain depth per line 288 -> ~18).
__global__ void k_deg(const int* __restrict__ row, const int* __restrict__ col,
                      const float* __restrict__ w,
                      float* __restrict__ cdeg_p, int* __restrict__ rcnt_p, int E) {
    int e = blockIdx.x * blockDim.x + threadIdx.x;
    if (e < E) {
        atomicAdd(&cdeg_p[(size_t)col[e] * PAD], w[e]);
        atomicAdd(&rcnt_p[(size_t)row[e] * PAD], 1);
    }
}

// Compact the padded counters; derive dg/dinv.
__global__ void k_derive(const float* __restrict__ cdeg_p, const int* __restrict__ rcnt_p,
                         float* __restrict__ dg, float* __restrict__ dinv,
                         int* __restrict__ rcnt_c, int N) {
    int n = blockIdx.x * blockDim.x + threadIdx.x;
    if (n < N) {
        float c = cdeg_p[(size_t)n * PAD];
        dg[n] = rsqrtf(c + 1.0f);
        dinv[n] = 1.0f / c;
        rcnt_c[n] = rcnt_p[(size_t)n * PAD];
    }
}

// ---- device-wide exclusive scan over rcnt_c ----
__global__ void __launch_bounds__(256) k_scan1(const int* __restrict__ cnt,
                                               int* __restrict__ pre,
                                               int* __restrict__ bsum, int N) {
    int t = threadIdx.x;
    int base = blockIdx.x * 1024 + t * 4;
    int v0 = 0, v1 = 0, v2 = 0, v3 = 0;
    if (base + 3 < N) {
        int4 q = *(const int4*)(cnt + base);
        v0 = q.x; v1 = q.y; v2 = q.z; v3 = q.w;
    } else {
        if (base     < N) v0 = cnt[base];
        if (base + 1 < N) v1 = cnt[base + 1];
        if (base + 2 < N) v2 = cnt[base + 2];
        if (base + 3 < N) v3 = cnt[base + 3];
    }
    int tt = v0 + v1 + v2 + v3;
    __shared__ int s[256];
    s[t] = tt; __syncthreads();
    for (int off = 1; off < 256; off <<= 1) {
        int v = (t >= off) ? s[t - off] : 0;
        __syncthreads();
        s[t] += v;
        __syncthreads();
    }
    int ex = (t == 0) ? 0 : s[t - 1];
    if (base     < N) pre[base]     = ex;
    if (base + 1 < N) pre[base + 1] = ex + v0;
    if (base + 2 < N) pre[base + 2] = ex + v0 + v1;
    if (base + 3 < N) pre[base + 3] = ex + v0 + v1 + v2;
    if (t == 255) bsum[blockIdx.x] = s[255];
}

__global__ void k_scan2(int* __restrict__ bsum, int B) {
    if (threadIdx.x == 0 && blockIdx.x == 0) {
        int run = 0;
        for (int i = 0; i < B; ++i) { int v = bsum[i]; bsum[i] = run; run += v; }
        bsum[B] = run;
    }
}

__global__ void __launch_bounds__(256) k_scan3(const int* __restrict__ bsum,
                                               int* __restrict__ rp, int* __restrict__ cur_p,
                                               int N, int B) {
    int i = blockIdx.x * 256 + threadIdx.x;
    if (i < N) {
        int v = rp[i] + bsum[i >> 10];
        rp[i] = v;
        cur_p[(size_t)i * PAD] = v;
    }
    if (i == 0) rp[N] = bsum[B];
}

__global__ void k_scatter(const int* __restrict__ row, const int* __restrict__ col,
                          const float* __restrict__ w,
                          const float* __restrict__ dg, const float* __restrict__ dinv,
                          int* __restrict__ cur_p, int* __restrict__ ci,
                          float* __restrict__ cwg, float* __restrict__ cws, int E) {
    int e = blockIdx.x * blockDim.x + threadIdx.x;
    if (e < E) {
        int r = row[e], c = col[e];
        float wf = w[e];
        int p = atomicAdd(&cur_p[(size_t)r * PAD], 1);
        ci[p] = c;
        cwg[p] = wf * dg[c];
        cws[p] = wf * dinv[c];
    }
}

__global__ void k_xcast(const float* __restrict__ x, u32* __restrict__ xb, int n2) {
    int i = blockIdx.x * blockDim.x + threadIdx.x;
    if (i < n2) {
        f2 v = ld2(x + i * 2);
        xb[i] = pbf(v.x, v.y);
    }
}

// Interleaved mirror layout: row r occupies 128 u32 (512 B):
//   IL[r*128 + 2*k]   = bf16 pair of GCN channel
//   IL[r*128 + 2*k+1] = bf16 pair of fp (scattering) channel
#define UN 8

__global__ void __launch_bounds__(256) k_step1(const int* __restrict__ rp, const int* __restrict__ ci,
                                               const float* __restrict__ cwg, const float* __restrict__ cws,
                                               const float* __restrict__ X, const u32* __restrict__ Xb,
                                               const float* __restrict__ dg,
                                               u32* __restrict__ il1, float* __restrict__ fp1, int N) {
    int t = threadIdx.x;
    int lane = t & 63;
    int r = blockIdx.x * 4 + (t >> 6);
    if (r >= N) return;
    int s = rp[r], e = rp[r + 1];
    float agx = 0.f, agy = 0.f, asx = 0.f, asy = 0.f;
    int j = s;
    for (; j + UN <= e; j += UN) {
        int jb = __builtin_amdgcn_readfirstlane(j);
        int c[UN]; float wg[UN], ws[UN];
#pragma unroll
        for (int u = 0; u < UN; ++u) {
            c[u]  = ci[jb + u];
            wg[u] = cwg[jb + u];
            ws[u] = cws[jb + u];
        }
        u32 pv[UN];
#pragma unroll
        for (int u = 0; u < UN; ++u) pv[u] = Xb[c[u] * 64 + lane];
#pragma unroll
        for (int u = 0; u < UN; ++u) {
            float vx, vy; ubf(pv[u], vx, vy);
            agx = fmaf(wg[u], vx, agx); agy = fmaf(wg[u], vy, agy);
            asx = fmaf(ws[u], vx, asx); asy = fmaf(ws[u], vy, asy);
        }
    }
    for (; j < e; ++j) {
        int jb = __builtin_amdgcn_readfirstlane(j);
        int c = ci[jb];
        float wg = cwg[jb], ws = cws[jb];
        float vx, vy; ubf(Xb[c * 64 + lane], vx, vy);
        agx = fmaf(wg, vx, agx); agy = fmaf(wg, vy, agy);
        asx = fmaf(ws, vx, asx); asy = fmaf(ws, vy, asy);
    }
    float g = dg[r];
    f2 xr = ld2(X + r * DF + lane * 2);
    float gox = (agx + g * xr.x) * g, goy = (agy + g * xr.y) * g;
    float sox = 0.5f * xr.x + 0.5f * asx, soy = 0.5f * xr.y + 0.5f * asy;
    uint2 o = { pbf(gox, goy), pbf(sox, soy) };
    *(uint2*)(il1 + r * 128 + 2 * lane) = o;
    st2(fp1 + r * DF + lane * 2, {sox, soy});
}

__global__ void __launch_bounds__(256) k_step23(const int* __restrict__ rp, const int* __restrict__ ci,
                                                const float* __restrict__ cwg, const float* __restrict__ cws,
                                                const u32* __restrict__ ils,
                                                const float* __restrict__ sfull,
                                                const float* __restrict__ dg,
                                                u32* __restrict__ ild,
                                                float* __restrict__ sdst,
                                                u32* __restrict__ hsb,
                                                u32* __restrict__ fpb,
                                                const int* __restrict__ mom, int N) {
    int t = threadIdx.x;
    int lane = t & 63;
    int r = blockIdx.x * 4 + (t >> 6);
    if (r >= N) return;
    int s = rp[r], e = rp[r + 1];
    float agx = 0.f, agy = 0.f, asx = 0.f, asy = 0.f;
    int j = s;
    for (; j + UN <= e; j += UN) {
        int jb = __builtin_amdgcn_readfirstlane(j);
        int c[UN]; float wg[UN], ws[UN];
#pragma unroll
        for (int u = 0; u < UN; ++u) {
            c[u]  = ci[jb + u];
            wg[u] = cwg[jb + u];
            ws[u] = cws[jb + u];
        }
        uint2 pv[UN];
#pragma unroll
        for (int u = 0; u < UN; ++u) pv[u] = *(const uint2*)(ils + (size_t)c[u] * 128 + 2 * lane);
#pragma unroll
        for (int u = 0; u < UN; ++u) {
            float gx, gy, sx, sy;
            ubf(pv[u].x, gx, gy);
            ubf(pv[u].y, sx, sy);
            agx = fmaf(wg[u], gx, agx); agy = fmaf(wg[u], gy, agy);
            asx = fmaf(ws[u], sx, asx); asy = fmaf(ws[u], sy, asy);
        }
    }
    for (; j < e; ++j) {
        int jb = __builtin_amdgcn_readfirstlane(j);
        int c = ci[jb];
        float wg = cwg[jb], ws = cws[jb];
        uint2 pv = *(const uint2*)(ils + (size_t)c * 128 + 2 * lane);
        float gx, gy, sx, sy;
        ubf(pv.x, gx, gy);
        ubf(pv.y, sx, sy);
        agx = fmaf(wg, gx, agx); agy = fmaf(wg, gy, agy);
        asx = fmaf(ws, sx, asx); asy = fmaf(ws, sy, asy);
    }
    float g = dg[r];
    float grx, gry; ubf(ils[r * 128 + 2 * lane], grx, gry);
    float gox = (agx + g * grx) * g, goy = (agy + g * gry) * g;
    f2 pvv = ld2(sfull + r * DF + lane * 2);
    float nvx = 0.5f * pvv.x + 0.5f * asx, nvy = 0.5f * pvv.y + 0.5f * asy;
    u32 fppack = pbf(nvx, nvy);
    uint2 o = { pbf(gox, goy), fppack };
    *(uint2*)(ild + r * 128 + 2 * lane) = o;
    st2(sdst + r * DF + lane * 2, {nvx, nvy});
    if (fpb != nullptr) fpb[r * 64 + lane] = fppack;
    float ddx = fabsf(pvv.x - nvx), ddy = fabsf(pvv.y - nvy);
    int m = decode_m(mom[0]);
    if (m != 1) { ddx = powf(ddx, (float)m); ddy = powf(ddy, (float)m); }
    hsb[r * 64 + lane] = pbf(ddx, ddy);
}

__global__ void __launch_bounds__(256) k_step4attn(const int* __restrict__ rp, const int* __restrict__ ci,
                                                   const float* __restrict__ cws,
                                                   const u32* __restrict__ il1, const u32* __restrict__ il2,
                                                   const u32* __restrict__ il3,
                                                   const u32* __restrict__ fp3b,
                                                   const float* __restrict__ sfull,
                                                   const u32* __restrict__ s1b, const u32* __restrict__ s2b,
                                                   const float* __restrict__ X, const float* __restrict__ a,
                                                   u32* __restrict__ hpb,
                                                   const int* __restrict__ mom, int N) {
    int t = threadIdx.x;
    int lane = t & 63;
    int r = blockIdx.x * 4 + (t >> 6);
    if (r >= N) return;
    int s = rp[r], e = rp[r + 1];
    float asx = 0.f, asy = 0.f;
    int j = s;
    for (; j + UN <= e; j += UN) {
        int jb = __builtin_amdgcn_readfirstlane(j);
        int c[UN]; float ws[UN];
#pragma unroll
        for (int u = 0; u < UN; ++u) {
            c[u]  = ci[jb + u];
            ws[u] = cws[jb + u];
        }
        u32 pv[UN];
#pragma unroll
        for (int u = 0; u < UN; ++u) pv[u] = fp3b[c[u] * 64 + lane];
#pragma unroll
        for (int u = 0; u < UN; ++u) {
            float sx, sy; ubf(pv[u], sx, sy);
            asx = fmaf(ws[u], sx, asx); asy = fmaf(ws[u], sy, asy);
        }
    }
    for (; j < e; ++j) {
        int jb = __builtin_amdgcn_readfirstlane(j);
        float ws = cws[jb];
        float sx, sy; ubf(fp3b[ci[jb] * 64 + lane], sx, sy);
        asx = fmaf(ws, sx, asx); asy = fmaf(ws, sy, asy);
    }
    f2 pvv = ld2(sfull + r * DF + lane * 2);
    float ddx = fabsf(pvv.x - (0.5f * pvv.x + 0.5f * asx));
    float ddy = fabsf(pvv.y - (0.5f * pvv.y + 0.5f * asy));
    int m = decode_m(mom[0]);
    if (m != 1) { ddx = powf(ddx, (float)m); ddy = powf(ddy, (float)m); }

    float hx[6], hy[6];
    ubf(il1[r * 128 + 2 * lane], hx[0], hy[0]);
    ubf(il2[r * 128 + 2 * lane], hx[1], hy[1]);
    ubf(il3[r * 128 + 2 * lane], hx[2], hy[2]);
    ubf(s1b[r * 64 + lane], hx[3], hy[3]);
    ubf(s2b[r * 64 + lane], hx[4], hy[4]);
    hx[5] = ddx; hy[5] = ddy;
#pragma unroll
    for (int c = 0; c < 3; ++c) {
        hx[c] = hx[c] > 0.f ? hx[c] : NEG * hx[c];
        hy[c] = hy[c] > 0.f ? hy[c] : NEG * hy[c];
    }
    f2 xr = ld2(X + r * DF + lane * 2);
    f2 a1 = ld2(a + lane * 2);
    f2 a2 = ld2(a + DF + lane * 2);
    float part[7];
    part[0] = fmaxf(xr.x, 0.f) * a1.x + fmaxf(xr.y, 0.f) * a1.y;
#pragma unroll
    for (int c = 0; c < 6; ++c)
        part[c + 1] = fmaxf(hx[c], 0.f) * a2.x + fmaxf(hy[c], 0.f) * a2.y;
#pragma unroll
    for (int k = 0; k < 7; ++k) {
        float v = part[k];
#pragma unroll
        for (int mm = 32; mm > 0; mm >>= 1) v += __shfl_xor(v, mm, 64);
        part[k] = v;
    }
    float ev[6], mx = -1e30f;
#pragma unroll
    for (int c = 0; c < 6; ++c) { ev[c] = part[0] + part[c + 1]; mx = fmaxf(mx, ev[c]); }
    float ssum = 0.f;
#pragma unroll
    for (int c = 0; c < 6; ++c) { ev[c] = __expf(ev[c] - mx); ssum += ev[c]; }
    float sc = 1.f / (6.f * ssum);
    float ox = 0.f, oy = 0.f;
#pragma unroll
    for (int c = 0; c < 6; ++c) { ox = fmaf(ev[c], hx[c], ox); oy = fmaf(ev[c], hy[c], oy); }
    hpb[r * 64 + lane] = pbf(ox * sc, oy * sc);
}

__global__ void __launch_bounds__(256) k_mlp2x(const u32* __restrict__ hpb,
                                               const float* __restrict__ W1, const float* __restrict__ b1,
                                               const float* __restrict__ W2, const float* __restrict__ b2,
                                               float* __restrict__ out, int N, int NT) {
    __shared__ unsigned short ylds[16][136];
    int t = threadIdx.x, lane = t & 63, wv = t >> 6;
    int n15 = lane & 15, quad = lane >> 4;
    s8v w1f[2][4], w2f[2][4];
    float bias1[2], bias2[2];
#pragma unroll
    for (int i = 0; i < 2; ++i) {
        int ct = wv + 4 * i;
        int rw = ct * 16 + n15;
#pragma unroll
        for (int q = 0; q < 4; ++q) {
            w1f[i][q] = pack8(W1 + rw * DF + q * 32 + quad * 8);
            w2f[i][q] = pack8(W2 + rw * DF + q * 32 + quad * 8);
        }
        bias1[i] = b1[rw];
        bias2[i] = b2[rw];
    }
    for (int tile = blockIdx.x; tile < NT; tile += gridDim.x) {
        int row0 = tile * 16;
        int rA = row0 + n15; if (rA >= N) rA = N - 1;
        s8v a1[4];
        const u32* src = hpb + (size_t)rA * 64;
#pragma unroll
        for (int q = 0; q < 4; ++q) a1[q] = load8p(src + q * 16 + quad * 4);
        f4v acc0 = {0.f, 0.f, 0.f, 0.f}, acc1 = {0.f, 0.f, 0.f, 0.f};
#pragma unroll
        for (int q = 0; q < 4; ++q) {
            acc0 = __builtin_amdgcn_mfma_f32_16x16x32_bf16(a1[q], w1f[0][q], acc0, 0, 0, 0);
            acc1 = __builtin_amdgcn_mfma_f32_16x16x32_bf16(a1[q], w1f[1][q], acc1, 0, 0, 0);
        }
        __syncthreads();
#pragma unroll
        for (int i = 0; i < 2; ++i) {
            int cb = (wv + 4 * i) * 16 + n15;
#pragma unroll
            for (int reg = 0; reg < 4; ++reg) {
                float v = (i == 0 ? acc0[reg] : acc1[reg]) + bias1[i];
                v = v > 0.f ? v : NEG * v;
                ylds[quad * 4 + reg][cb] = f2bf(v);
            }
        }
        __syncthreads();
        s8v a2[4];
#pragma unroll
        for (int q = 0; q < 4; ++q)
            a2[q] = *(const s8v*)&ylds[n15][q * 32 + quad * 8];
        f4v o0 = {0.f, 0.f, 0.f, 0.f}, o1 = {0.f, 0.f, 0.f, 0.f};
#pragma unroll
        for (int q = 0; q < 4; ++q) {
            o0 = __builtin_amdgcn_mfma_f32_16x16x32_bf16(a2[q], w2f[0][q], o0, 0, 0, 0);
            o1 = __builtin_amdgcn_mfma_f32_16x16x32_bf16(a2[q], w2f[1][q], o1, 0, 0, 0);
        }
#pragma unroll
        for (int i = 0; i < 2; ++i) {
            int cb = (wv + 4 * i) * 16 + n15;
#pragma unroll
            for (int reg = 0; reg < 4; ++reg) {
                int rr = row0 + quad * 4 + reg;
                if (rr < N) {
                    float v = (i == 0 ? o0[reg] : o1[reg]) + bias2[i];
                    out[(size_t)rr * DF + cb] = v > 0.f ? v : NEG * v;
                }
            }
        }
    }
}

extern "C" void kernel_launch(void* const* d_in, const int* in_sizes, int n_in,
                              void* d_out, int out_size, void* d_ws, size_t ws_size,
                              hipStream_t stream) {
    const float* X  = (const float*)d_in[0];
    const int*   ei = (const int*)d_in[1];
    const float* ew = (const float*)d_in[2];
    const float* W1 = (const float*)d_in[3];
    const float* b1 = (const float*)d_in[4];
    const float* W2 = (const float*)d_in[5];
    const float* b2 = (const float*)d_in[6];
    const float* a  = (const float*)d_in[7];
    const int*  mom = (const int*)d_in[8];

    const int N = in_sizes[0] / DF;
    const int E = in_sizes[2];
    const int* row = ei;
    const int* col = ei + E;
    const size_t ND = (size_t)N * DF;
    const size_t ND2 = ND / 2;

    char* p = (char*)d_ws;
    auto alloc = [&](size_t bytes) -> void* {
        char* r = p;
        p += (bytes + 255) & ~(size_t)255;
        return (void*)r;
    };
    float* P   = (float*)alloc(ND * 4);
    float* Q   = (float*)alloc(ND * 4);
    u32*   Xb  = (u32*)alloc(ND2 * 4);
    u32*   IL1 = (u32*)alloc(ND * 4);
    u32*   IL2 = (u32*)alloc(ND * 4);
    u32*   IL3 = (u32*)alloc(ND * 4);
    u32*   FP3 = (u32*)alloc(ND2 * 4);
    u32*   S1b = (u32*)alloc(ND2 * 4);
    u32*   S2b = (u32*)alloc(ND2 * 4);
    u32*   Qb  = (u32*)alloc(ND2 * 4);
    float* cdeg_p = (float*)alloc((size_t)N * PAD * 4);  // line-padded counters
    int*   rcnt_p = (int*)alloc((size_t)N * PAD * 4);
    int*   cur_p  = (int*)alloc((size_t)N * PAD * 4);
    int*   rcnt_c = (int*)alloc((size_t)N * 4);
    float* dg   = (float*)alloc((size_t)N * 4);
    float* dinv = (float*)alloc((size_t)N * 4);
    int*   rp   = (int*)alloc((size_t)(N + 1) * 4);
    int*   bsum = (int*)alloc((size_t)256 * 4);
    int*   ci   = (int*)alloc((size_t)E * 4);
    float* cwg  = (float*)alloc((size_t)E * 4);
    float* cws  = (float*)alloc((size_t)E * 4);

    if ((size_t)(p - (char*)d_ws) > ws_size) {
        k_sentinel<<<(out_size + 255) / 256, 256, 0, stream>>>((float*)d_out, out_size);
        return;
    }

    hipMemsetAsync(cdeg_p, 0, (size_t)N * PAD * 4, stream);
    hipMemsetAsync(rcnt_p, 0, (size_t)N * PAD * 4, stream);

    int eb = (E + 255) / 256;
    k_deg<<<eb, 256, 0, stream>>>(row, col, ew, cdeg_p, rcnt_p, E);
    k_derive<<<(N + 255) / 256, 256, 0, stream>>>(cdeg_p, rcnt_p, dg, dinv, rcnt_c, N);
    k_xcast<<<(int)((ND2 + 255) / 256), 256, 0, stream>>>(X, Xb, (int)ND2);

    int SB = (N + 1023) / 1024;
    k_scan1<<<SB, 256, 0, stream>>>(rcnt_c, rp, bsum, N);
    k_scan2<<<1, 64, 0, stream>>>(bsum, SB);
    k_scan3<<<(N + 255) / 256, 256, 0, stream>>>(bsum, rp, cur_p, N, SB);

    k_scatter<<<eb, 256, 0, stream>>>(row, col, ew, dg, dinv, cur_p, ci, cwg, cws, E);

    int rb = (N + 3) / 4;
    k_step1<<<rb, 256, 0, stream>>>(rp, ci, cwg, cws, X, Xb, dg, IL1, P, N);
    k_step23<<<rb, 256, 0, stream>>>(rp, ci, cwg, cws, IL1, P, dg, IL2, Q, S1b, (u32*)nullptr, mom, N);
    k_step23<<<rb, 256, 0, stream>>>(rp, ci, cwg, cws, IL2, Q, dg, IL3, P, S2b, FP3, mom, N);
    k_step4attn<<<rb, 256, 0, stream>>>(rp, ci, cws, IL1, IL2, IL3, FP3, P, S1b, S2b, X, a, Qb, mom, N);

    int NT = (N + 15) / 16;
    int gb = NT < 1024 ? NT : 1024;
    k_mlp2x<<<gb, 256, 0, stream>>>(Qb, W1, b1, W2, b2, (float*)d_out, N, NT);
}